// Round 16
// baseline (3108.129 us; speedup 1.0000x reference)
//
#include <hip/hip_runtime.h>

// InverseRecurrentLayer v15 — HBM off the step-critical-path.
// Protocol = v13 tag-in-data (proven): no flags, no per-step barriers; 16B state
// chunks carry a 1-bit generation tag (LSB of h[7], single dwordx4 -> atomic-16B).
// NEW: out values register-buffered (ob[8][4]) and flushed once per 8 steps; h
// prefetched 8 steps at a time (hb[8][4]). Both drain inside the NEXT stage's
// waitvm0, overlapped with the tag retry -> the ~1us HBM ack that sat in every
// prior variant's chain (vmcnt is FIFO!) is amortized to ~0.13us/step.
// 8-step unrolled loop makes slot/tag/hb/ob indices compile-time (rule #20).
// Producer per-step drain = 4 state-store MALL acks only (also reg-reuse safety
// for inline-asm stores). Depth-2 slot safety: all-to-all gate back-pressure
// (writing t+2 requires all wrote t+1 requires all read t).

#define TSTEPS 512

typedef __attribute__((ext_vector_type(4))) float f32x4;
typedef __attribute__((ext_vector_type(8))) _Float16 f16x8;
typedef unsigned long long u64;
typedef unsigned int u32;

union pk2 { _Float16 h[2]; u32 u; };
union chunk16 { f32x4 f; u32 d[4]; _Float16 h[8]; };

__device__ __forceinline__ f32x4 mfma16(f16x8 a, f16x8 b, f32x4 c){
  return __builtin_amdgcn_mfma_f32_16x16x32_f16(a, b, c, 0, 0, 0);
}
__device__ __forceinline__ void waitvm0(){ asm volatile("s_waitcnt vmcnt(0)" ::: "memory"); }
__device__ __forceinline__ f32x4 gload_sc1_b128(const void* p){
  f32x4 r; asm volatile("global_load_dwordx4 %0, %1, off sc1" : "=v"(r) : "v"(p) : "memory"); return r;
}
__device__ __forceinline__ void gstore_sc1_b128(void* p, f32x4 d){
  asm volatile("global_store_dwordx4 %0, %1, off sc1" :: "v"(p), "v"(d) : "memory");
}
__device__ __forceinline__ void u32store_mall(u32* p, u32 v){
  __hip_atomic_store(p, v, __ATOMIC_RELAXED, __HIP_MEMORY_SCOPE_AGENT);
}
__device__ __forceinline__ u32 u32load_mall(const u32* p){
  return __hip_atomic_load(p, __ATOMIC_RELAXED, __HIP_MEMORY_SCOPE_AGENT);
}

// ---------------- (1) weight convert ----------------
__global__ void cvt_wr(const float* __restrict__ W, const float* __restrict__ R,
                       _Float16* __restrict__ Wa, _Float16* __restrict__ Wb,
                       _Float16* __restrict__ Rt){
  const int n  = gridDim.x * blockDim.x;
  const int id = blockIdx.x * blockDim.x + threadIdx.x;
  for (int i = id; i < 1024*1024; i += n){
    const float v = W[i];
    Wa[i] = (_Float16)v;                              // Wa[u][k] = W[u][k]  (W^T op)
    const int k = i >> 10, u = i & 1023;
    Wb[u*1024 + k] = (_Float16)v;                     // Wb[u][k] = W[k][u]  (W op)
  }
  for (int i = id; i < 512*1024; i += n){
    const int f = i >> 10, u = i & 1023;
    Rt[u*512 + f] = (_Float16)R[i];                   // Rt[u][f] = R[f][u]
  }
}

// ---------------- (2) h prepass ----------------
__global__ __launch_bounds__(512, 2) void h_prepass(
    const float* __restrict__ inputs, const _Float16* __restrict__ Rt,
    const float* __restrict__ bias, float* __restrict__ out){
  const int t  = blockIdx.x;
  const int w  = threadIdx.x >> 6, l = threadIdx.x & 63;
  const int lr = l & 15, lg = l >> 4;
  const int b0 = (w >> 1) * 16;
  const int c0 = (w & 1) * 512;

  f32x4 acc[32];
  #pragma unroll
  for (int n = 0; n < 32; ++n) acc[n] = (f32x4){0.f,0.f,0.f,0.f};

  for (int kc = 0; kc < 16; ++kc){
    const float* ip = inputs + (size_t)(b0 + lr)*262144 + (size_t)t*512 + kc*32 + lg*8;
    float4 xa = *(const float4*)ip, xb = *(const float4*)(ip + 4);
    f16x8 a;
    a[0]=(_Float16)xa.x; a[1]=(_Float16)xa.y; a[2]=(_Float16)xa.z; a[3]=(_Float16)xa.w;
    a[4]=(_Float16)xb.x; a[5]=(_Float16)xb.y; a[6]=(_Float16)xb.z; a[7]=(_Float16)xb.w;
    const _Float16* rp = Rt + (size_t)(c0 + lr)*512 + kc*32 + lg*8;
    #pragma unroll
    for (int n = 0; n < 32; ++n){
      f16x8 b = *(const f16x8*)(rp + (size_t)n*(16*512));
      acc[n] = mfma16(a, b, acc[n]);
    }
  }
  #pragma unroll
  for (int n = 0; n < 32; ++n){
    const int u = c0 + n*16 + lr;
    const float bu = bias[u];
    #pragma unroll
    for (int j = 0; j < 4; ++j)
      out[(size_t)t*65536 + (size_t)(b0 + lg*4 + j)*1024 + u] = acc[n][j] + bu;
  }
}

// ---------------- (3) scan ----------------
__global__ __launch_bounds__(512, 2) void irl_scan(
    const _Float16* __restrict__ Wa, const _Float16* __restrict__ Wb,
    const float* __restrict__ x0, float* __restrict__ out,
    unsigned short* __restrict__ st, unsigned* __restrict__ flags)
{
  __shared__ char alds[16 * 2048];     // row-group state [16 rows][1024 k], swizzled

  const int tid = threadIdx.x;
  const int w   = tid >> 6;            // wave = n-tile owner AND producer-w stager
  const int l   = tid & 63;
  const int lr  = l & 15;
  const int lg  = l >> 4;
  const int cblk = blockIdx.x & 7;     // col-split (producer id in group)
  const int grp  = blockIdx.x >> 3;    // row-group
  const int col0 = cblk << 7;          // 128 cols per block
  const int r0   = grp << 4;           // 16 rows per group
  const int u    = col0 + w*16 + lr;
  unsigned* myf  = flags + (((grp << 3) + cblk) << 4);

  // ---- state[0] <- x0 : tagged 16B chunks into slot 0 (tag for t=0 is 1) ----
  if (tid < 256){
    const int row = tid >> 4, ch = tid & 15;
    chunk16 c;
    #pragma unroll
    for (int j = 0; j < 8; ++j) c.h[j] = (_Float16)x0[col0 + ch*8 + j];
    c.d[3] = (c.d[3] & ~0x10000u) | 0x10000u;
    gstore_sc1_b128((char*)st + (size_t)(r0 + row)*2048 + col0*2 + ch*16, c.f);
  }
  waitvm0();
  __syncthreads();
  if (tid == 0) u32store_mall(myf, 1u);
  // one-time init gate (proven r11/r13 pattern): kills cross-replay stale slot 0
  if (tid < 64){
    const int src = (tid < 8) ? tid : 0;
    const unsigned* pf = flags + (((grp << 3) + src) << 4);
    for (;;){
      unsigned v = u32load_mall(pf);
      if (__all((int)(v >= 1u))) break;
      __builtin_amdgcn_s_sleep(1);
    }
  }
  __syncthreads();

  f16x8 wf[32];                        // current phase, full K=1024 (128 VGPR)
  for (int tb = 0; tb < TSTEPS; tb += 8){
    if ((tb & 63) == 0){               // phase boundary (64 % 8 == 0)
      const int ph = (tb >> 6) & 1;    // 1 -> W (Wb), 0 -> W^T (Wa)
      const _Float16* Wsel = ph ? Wb : Wa;
      #pragma unroll
      for (int i = 0; i < 32; ++i)
        wf[i] = *(const f16x8*)(Wsel + (size_t)u*1024 + i*32 + lg*8);
    }

    // batched h prefetch for 8 steps (drains at ti=0's stage waitvm0)
    float hb[8][4];
    #pragma unroll
    for (int ti = 0; ti < 8; ++ti){
      #pragma unroll
      for (int j = 0; j < 4; ++j)
        hb[ti][j] = out[(size_t)(tb + ti)*65536 + (size_t)(r0 + lg*4 + j)*1024 + u];
    }

    float ob[8][4];                    // out buffer, flushed at tb end
    #pragma unroll
    for (int ti = 0; ti < 8; ++ti){
      const u32 tag_exp = (((u32)ti >> 1) & 1u) ^ 1u;        // static after unroll
      const u32 tag_nxt = (((u32)(ti + 1) >> 1) & 1u) ^ 1u;  // static after unroll

      // ---- tag-verified stage (gate merged into the data load) ----
      const char* base = (const char*)st + ((size_t)(ti & 1) << 17)
                       + (size_t)r0*2048 + w*256 + lr*16;
      chunk16 q[4];
      for (;;){
        #pragma unroll
        for (int i = 0; i < 4; ++i)
          q[i].f = gload_sc1_b128(base + (size_t)(i*4 + lg)*2048);
        waitvm0();
        int ok = 1;
        #pragma unroll
        for (int i = 0; i < 4; ++i)
          ok &= (int)(((q[i].d[3] >> 16) & 1u) == tag_exp);
        if (__all(ok)) break;
        __builtin_amdgcn_s_sleep(1);
      }
      __syncthreads();                 // prev-step MFMA reads of alds complete
      #pragma unroll
      for (int i = 0; i < 4; ++i){
        const int row = i*4 + lg, c = w*256 + lr*16;
        *(f32x4*)(alds + row*2048 + (c ^ ((row & 7) << 4))) = q[i].f;
      }
      __syncthreads();

      // ---- recurrent GEMM: 32 MFMAs, 2 chains ----
      f32x4 ac0 = {0.f,0.f,0.f,0.f}, ac1 = ac0;
      #pragma unroll
      for (int i = 0; i < 32; i += 2){
        f16x8 a0 = *(const f16x8*)(alds + lr*2048 + ((i*64 + lg*16) ^ ((lr & 7) << 4)));
        f16x8 a1 = *(const f16x8*)(alds + lr*2048 + (((i+1)*64 + lg*16) ^ ((lr & 7) << 4)));
        ac0 = mfma16(a0, wf[i], ac0);
        ac1 = mfma16(a1, wf[i+1], ac1);
      }
      const f32x4 acc = ac0 + ac1;

      // ---- epilogue: tanh -> ob (registers); tagged state stores; MALL drain ----
      char* nbB = (char*)st + ((size_t)((ti & 1) ^ 1) << 17);
      chunk16 cst[4];
      #pragma unroll
      for (int j = 0; j < 4; ++j){
        const float v = tanhf(acc[j] + hb[ti][j]);
        ob[ti][j] = v;
        pk2 me; me.h[0] = (_Float16)v; me.h[1] = (_Float16)0.f;
        const u32 two = (me.u & 0xffffu) | ((u32)__shfl_xor((int)me.u, 1) << 16);
        const u32 lo4 = two, hi4 = (u32)__shfl_xor((int)two, 2);
        cst[j].d[0] = lo4;
        cst[j].d[1] = hi4;
        cst[j].d[2] = (u32)__shfl_xor((int)lo4, 4);
        cst[j].d[3] = ((u32)__shfl_xor((int)hi4, 4) & ~0x10000u) | (tag_nxt << 16);
      }
      if (!(lr & 7)){
        #pragma unroll
        for (int j = 0; j < 4; ++j)
          gstore_sc1_b128(nbB + (size_t)(r0 + lg*4 + j)*2048 + (size_t)(u & ~7)*2, cst[j].f);
      }
      waitvm0();                       // state MALL ack (visibility + asm-reg safety)
    }

    // ---- flush out: 32 NT stores; drain folds into next tb's first stage ----
    #pragma unroll
    for (int ti = 0; ti < 8; ++ti){
      #pragma unroll
      for (int j = 0; j < 4; ++j)
        __builtin_nontemporal_store(ob[ti][j],
          out + (size_t)(tb + ti)*65536 + (size_t)(r0 + lg*4 + j)*1024 + u);
    }
  }
}

extern "C" void kernel_launch(void* const* d_in, const int* in_sizes, int n_in,
                              void* d_out, int out_size, void* d_ws, size_t ws_size,
                              hipStream_t stream){
  (void)in_sizes; (void)n_in; (void)out_size; (void)ws_size;
  const float* inputs = (const float*)d_in[0];   // [64,512,512] f32
  const float* R      = (const float*)d_in[1];   // [512,1024]  f32
  const float* W      = (const float*)d_in[2];   // [1024,1024] f32
  const float* bias   = (const float*)d_in[3];   // [1024]      f32
  const float* x0     = (const float*)d_in[4];   // [1024]      f32
  float* out = (float*)d_out;                    // [512,64,1024] f32 (h, then states)

  char* ws = (char*)d_ws;
  unsigned* flags     = (unsigned*)ws;                    // 4 KB (init gate only)
  unsigned short* st  = (unsigned short*)(ws + 4096);     // 2 x 64x1024 fp16 (256 KB)
  _Float16* Rt = (_Float16*)(ws + (512<<10));             // 1 MB  @ 0.5 MB
  _Float16* Wa = (_Float16*)(ws + (2u<<20));              // 2 MB  @ 2 MB
  _Float16* Wb = (_Float16*)(ws + (4u<<20));              // 2 MB  @ 4 MB

  (void)hipMemsetAsync(flags, 0, 4096, stream);
  hipLaunchKernelGGL(cvt_wr,    dim3(1024), dim3(256), 0, stream, W, R, Wa, Wb, Rt);
  hipLaunchKernelGGL(h_prepass, dim3(512),  dim3(512), 0, stream, inputs, Rt, bias, out);
  hipLaunchKernelGGL(irl_scan,  dim3(32),   dim3(512), 0, stream, Wa, Wb, x0, out, st, flags);
}

// Round 17
// 1866.078 us; speedup vs baseline: 1.6656x; 1.6656x over previous
//
#include <hip/hip_runtime.h>

// InverseRecurrentLayer v16 — v13 tag-in-data protocol + HBM-ack removal.
//  (1) out stores are PLAIN (not nontemporal): they ack at local XCD L2 (~250cy
//      writeback) instead of HBM (~2000cy). vmcnt is FIFO, so v11/v13/v14's out
//      NT-store HBM acks sat inside the NEXT stage drain every step. L2 pollution
//      is harmless here (scan reads only small Wa/Wb slices + streams h once).
//  (2) h(t+1) prefetched right after the LDS stage (before MFMA): its L3/HBM miss
//      overlaps compute + next poll instead of the stage drain. +4 VGPR only
//      (v15's 8-step register buffering spilled; reverted).
//  Protocol unchanged from v13 (validated): 16B state chunks carry a 1-bit gen
//  tag (LSB of h[7], single dwordx4 = no torn reads); consumer stage-load retries
//  until tags match; no flags, no per-step barriers; one-time init gate.

#define TSTEPS 512

typedef __attribute__((ext_vector_type(4))) float f32x4;
typedef __attribute__((ext_vector_type(8))) _Float16 f16x8;
typedef unsigned int u32;

union pk2 { _Float16 h[2]; u32 u; };
union chunk16 { f32x4 f; u32 d[4]; _Float16 h[8]; };

__device__ __forceinline__ f32x4 mfma16(f16x8 a, f16x8 b, f32x4 c){
  return __builtin_amdgcn_mfma_f32_16x16x32_f16(a, b, c, 0, 0, 0);
}
__device__ __forceinline__ void waitvm0(){ asm volatile("s_waitcnt vmcnt(0)" ::: "memory"); }
__device__ __forceinline__ f32x4 gload_sc1_b128(const void* p){
  f32x4 r; asm volatile("global_load_dwordx4 %0, %1, off sc1" : "=v"(r) : "v"(p) : "memory"); return r;
}
__device__ __forceinline__ void gstore_sc1_b128(void* p, f32x4 d){
  asm volatile("global_store_dwordx4 %0, %1, off sc1" :: "v"(p), "v"(d) : "memory");
}
__device__ __forceinline__ void u32store_mall(u32* p, u32 v){
  __hip_atomic_store(p, v, __ATOMIC_RELAXED, __HIP_MEMORY_SCOPE_AGENT);
}
__device__ __forceinline__ u32 u32load_mall(const u32* p){
  return __hip_atomic_load(p, __ATOMIC_RELAXED, __HIP_MEMORY_SCOPE_AGENT);
}

// ---------------- (1) weight convert ----------------
__global__ void cvt_wr(const float* __restrict__ W, const float* __restrict__ R,
                       _Float16* __restrict__ Wa, _Float16* __restrict__ Wb,
                       _Float16* __restrict__ Rt){
  const int n  = gridDim.x * blockDim.x;
  const int id = blockIdx.x * blockDim.x + threadIdx.x;
  for (int i = id; i < 1024*1024; i += n){
    const float v = W[i];
    Wa[i] = (_Float16)v;                              // Wa[u][k] = W[u][k]  (W^T op)
    const int k = i >> 10, u = i & 1023;
    Wb[u*1024 + k] = (_Float16)v;                     // Wb[u][k] = W[k][u]  (W op)
  }
  for (int i = id; i < 512*1024; i += n){
    const int f = i >> 10, u = i & 1023;
    Rt[u*512 + f] = (_Float16)R[i];                   // Rt[u][f] = R[f][u]
  }
}

// ---------------- (2) h prepass ----------------
__global__ __launch_bounds__(512, 2) void h_prepass(
    const float* __restrict__ inputs, const _Float16* __restrict__ Rt,
    const float* __restrict__ bias, float* __restrict__ out){
  const int t  = blockIdx.x;
  const int w  = threadIdx.x >> 6, l = threadIdx.x & 63;
  const int lr = l & 15, lg = l >> 4;
  const int b0 = (w >> 1) * 16;
  const int c0 = (w & 1) * 512;

  f32x4 acc[32];
  #pragma unroll
  for (int n = 0; n < 32; ++n) acc[n] = (f32x4){0.f,0.f,0.f,0.f};

  for (int kc = 0; kc < 16; ++kc){
    const float* ip = inputs + (size_t)(b0 + lr)*262144 + (size_t)t*512 + kc*32 + lg*8;
    float4 xa = *(const float4*)ip, xb = *(const float4*)(ip + 4);
    f16x8 a;
    a[0]=(_Float16)xa.x; a[1]=(_Float16)xa.y; a[2]=(_Float16)xa.z; a[3]=(_Float16)xa.w;
    a[4]=(_Float16)xb.x; a[5]=(_Float16)xb.y; a[6]=(_Float16)xb.z; a[7]=(_Float16)xb.w;
    const _Float16* rp = Rt + (size_t)(c0 + lr)*512 + kc*32 + lg*8;
    #pragma unroll
    for (int n = 0; n < 32; ++n){
      f16x8 b = *(const f16x8*)(rp + (size_t)n*(16*512));
      acc[n] = mfma16(a, b, acc[n]);
    }
  }
  #pragma unroll
  for (int n = 0; n < 32; ++n){
    const int u = c0 + n*16 + lr;
    const float bu = bias[u];
    #pragma unroll
    for (int j = 0; j < 4; ++j)
      out[(size_t)t*65536 + (size_t)(b0 + lg*4 + j)*1024 + u] = acc[n][j] + bu;
  }
}

// ---------------- (3) scan ----------------
__global__ __launch_bounds__(512, 2) void irl_scan(
    const _Float16* __restrict__ Wa, const _Float16* __restrict__ Wb,
    const float* __restrict__ x0, float* __restrict__ out,
    unsigned short* __restrict__ st, unsigned* __restrict__ flags)
{
  __shared__ char alds[16 * 2048];     // row-group state [16 rows][1024 k], swizzled

  const int tid = threadIdx.x;
  const int w   = tid >> 6;            // wave = n-tile owner AND producer-w stager
  const int l   = tid & 63;
  const int lr  = l & 15;
  const int lg  = l >> 4;
  const int cblk = blockIdx.x & 7;     // col-split (producer id in group)
  const int grp  = blockIdx.x >> 3;    // row-group
  const int col0 = cblk << 7;          // 128 cols per block
  const int r0   = grp << 4;           // 16 rows per group
  const int u    = col0 + w*16 + lr;
  unsigned* myf  = flags + (((grp << 3) + cblk) << 4);

  // ---- state[0] <- x0 : tagged 16B chunks into slot 0 (tag for t=0 is 1) ----
  if (tid < 256){
    const int row = tid >> 4, ch = tid & 15;
    chunk16 c;
    #pragma unroll
    for (int j = 0; j < 8; ++j) c.h[j] = (_Float16)x0[col0 + ch*8 + j];
    c.d[3] |= 0x10000u;
    gstore_sc1_b128((char*)st + (size_t)(r0 + row)*2048 + col0*2 + ch*16, c.f);
  }
  waitvm0();
  __syncthreads();
  if (tid == 0) u32store_mall(myf, 1u);
  // one-time init gate (proven r11/r13 pattern): kills cross-replay stale slot 0
  if (tid < 64){
    const int src = (tid < 8) ? tid : 0;
    const unsigned* pf = flags + (((grp << 3) + src) << 4);
    for (;;){
      unsigned v = u32load_mall(pf);
      if (__all((int)(v >= 1u))) break;
      __builtin_amdgcn_s_sleep(1);
    }
  }
  __syncthreads();

  // h prefetch for t=0
  float hv[4];
  #pragma unroll
  for (int j = 0; j < 4; ++j)
    hv[j] = out[(size_t)(r0 + lg*4 + j)*1024 + u];

  unsigned cur = 0;
  int pp = -1;
  f16x8 wf[32];                        // current phase, full K=1024
  for (int t = 0; t < TSTEPS; ++t){
    const int ph = (t >> 6) & 1;       // 1 -> W (Wb), 0 -> W^T (Wa)
    if (ph != pp){
      pp = ph;
      const _Float16* Wsel = ph ? Wb : Wa;
      #pragma unroll
      for (int i = 0; i < 32; ++i)
        wf[i] = *(const f16x8*)(Wsel + (size_t)u*1024 + i*32 + lg*8);
    }

    // ---- tag-verified stage: gate merged into the data load (retry until gen t) ----
    const u32 tag_exp = (((u32)t >> 1) & 1u) ^ 1u;
    const char* base = (const char*)st + ((size_t)cur << 17)
                     + (size_t)r0*2048 + w*256 + lr*16;
    chunk16 q[4];
    for (;;){
      #pragma unroll
      for (int i = 0; i < 4; ++i)
        q[i].f = gload_sc1_b128(base + (size_t)(i*4 + lg)*2048);
      waitvm0();
      int ok = 1;
      #pragma unroll
      for (int i = 0; i < 4; ++i)
        ok &= (int)(((q[i].d[3] >> 16) & 1u) == tag_exp);
      if (__all(ok)) break;
      __builtin_amdgcn_s_sleep(1);
    }
    __syncthreads();                   // prev-step MFMA reads of alds complete
    #pragma unroll
    for (int i = 0; i < 4; ++i){
      const int row = i*4 + lg, c = w*256 + lr*16;
      *(f32x4*)(alds + row*2048 + (c ^ ((row & 7) << 4))) = q[i].f;
    }
    __syncthreads();

    // ---- h prefetch for t+1 (plain loads; miss overlaps MFMA + next poll) ----
    float hvn[4];
    {
      const int tn = (t < TSTEPS - 1) ? t + 1 : t;
      #pragma unroll
      for (int j = 0; j < 4; ++j)
        hvn[j] = out[(size_t)tn*65536 + (size_t)(r0 + lg*4 + j)*1024 + u];
    }

    // ---- recurrent GEMM: 32 MFMAs, 2 chains ----
    f32x4 ac0 = {0.f,0.f,0.f,0.f}, ac1 = ac0;
    #pragma unroll
    for (int i = 0; i < 32; i += 2){
      f16x8 a0 = *(const f16x8*)(alds + lr*2048 + ((i*64 + lg*16) ^ ((lr & 7) << 4)));
      f16x8 a1 = *(const f16x8*)(alds + lr*2048 + (((i+1)*64 + lg*16) ^ ((lr & 7) << 4)));
      ac0 = mfma16(a0, wf[i], ac0);
      ac1 = mfma16(a1, wf[i+1], ac1);
    }
    const f32x4 acc = ac0 + ac1;

    // ---- epilogue: all tagged state stores FIRST, then plain (L2) out stores ----
    char* nbB = (char*)st + ((size_t)(cur ^ 1u) << 17);
    const u32 tag_nxt = (((u32)(t + 1) >> 1) & 1u) ^ 1u;
    float vv[4];
    chunk16 cst[4];
    #pragma unroll
    for (int j = 0; j < 4; ++j){
      const float v = tanhf(acc[j] + hv[j]);
      vv[j] = v;
      pk2 me; me.h[0] = (_Float16)v; me.h[1] = (_Float16)0.f;
      const u32 two = (me.u & 0xffffu) | ((u32)__shfl_xor((int)me.u, 1) << 16);
      const u32 lo4 = two, hi4 = (u32)__shfl_xor((int)two, 2);
      cst[j].d[0] = lo4;
      cst[j].d[1] = hi4;
      cst[j].d[2] = (u32)__shfl_xor((int)lo4, 4);
      cst[j].d[3] = ((u32)__shfl_xor((int)hi4, 4) & ~0x10000u) | (tag_nxt << 16);
    }
    if (!(lr & 7)){
      #pragma unroll
      for (int j = 0; j < 4; ++j)
        gstore_sc1_b128(nbB + (size_t)(r0 + lg*4 + j)*2048 + (size_t)(u & ~7)*2, cst[j].f);
    }
    #pragma unroll
    for (int j = 0; j < 4; ++j)       // PLAIN stores: ack at local L2, lazy HBM drain
      out[(size_t)t*65536 + (size_t)(r0 + lg*4 + j)*1024 + u] = vv[j];

    #pragma unroll
    for (int j = 0; j < 4; ++j) hv[j] = hvn[j];
    cur ^= 1u;
  }
}

extern "C" void kernel_launch(void* const* d_in, const int* in_sizes, int n_in,
                              void* d_out, int out_size, void* d_ws, size_t ws_size,
                              hipStream_t stream){
  (void)in_sizes; (void)n_in; (void)out_size; (void)ws_size;
  const float* inputs = (const float*)d_in[0];   // [64,512,512] f32
  const float* R      = (const float*)d_in[1];   // [512,1024]  f32
  const float* W      = (const float*)d_in[2];   // [1024,1024] f32
  const float* bias   = (const float*)d_in[3];   // [1024]      f32
  const float* x0     = (const float*)d_in[4];   // [1024]      f32
  float* out = (float*)d_out;                    // [512,64,1024] f32 (h, then states)

  char* ws = (char*)d_ws;
  unsigned* flags     = (unsigned*)ws;                    // 4 KB (init gate only)
  unsigned short* st  = (unsigned short*)(ws + 4096);     // 2 x 64x1024 fp16 (256 KB)
  _Float16* Rt = (_Float16*)(ws + (512<<10));             // 1 MB  @ 0.5 MB
  _Float16* Wa = (_Float16*)(ws + (2u<<20));              // 2 MB  @ 2 MB
  _Float16* Wb = (_Float16*)(ws + (4u<<20));              // 2 MB  @ 4 MB

  (void)hipMemsetAsync(flags, 0, 4096, stream);
  hipLaunchKernelGGL(cvt_wr,    dim3(1024), dim3(256), 0, stream, W, R, Wa, Wb, Rt);
  hipLaunchKernelGGL(h_prepass, dim3(512),  dim3(512), 0, stream, inputs, Rt, bias, out);
  hipLaunchKernelGGL(irl_scan,  dim3(32),   dim3(512), 0, stream, Wa, Wb, x0, out, st, flags);
}

// Round 18
// 1815.229 us; speedup vs baseline: 1.7123x; 1.0280x over previous
//
#include <hip/hip_runtime.h>

// InverseRecurrentLayer v17 — v16 scan FROZEN + coalesced preprocessing.
// v16 confirmed the vmcnt-FIFO/HBM-ack theory (scan 1950->1510us). Remaining
// non-scan time ~356us vs ~35us roofline: h_prepass A-loads were uncoalesced
// (1MB lane stride), cvt transposes did scattered 2B writes. v17: prepass
// stages the inputs tile into LDS with coalesced float4 loads (f16, swizzled);
// cvt uses 64x64 LDS-tiled transposes. Scan byte-identical to v16.

#define TSTEPS 512

typedef __attribute__((ext_vector_type(4))) float f32x4;
typedef __attribute__((ext_vector_type(8))) _Float16 f16x8;
typedef unsigned int u32;

union pk2 { _Float16 h[2]; u32 u; };
union chunk16 { f32x4 f; u32 d[4]; _Float16 h[8]; };

__device__ __forceinline__ f32x4 mfma16(f16x8 a, f16x8 b, f32x4 c){
  return __builtin_amdgcn_mfma_f32_16x16x32_f16(a, b, c, 0, 0, 0);
}
__device__ __forceinline__ void waitvm0(){ asm volatile("s_waitcnt vmcnt(0)" ::: "memory"); }
__device__ __forceinline__ f32x4 gload_sc1_b128(const void* p){
  f32x4 r; asm volatile("global_load_dwordx4 %0, %1, off sc1" : "=v"(r) : "v"(p) : "memory"); return r;
}
__device__ __forceinline__ void gstore_sc1_b128(void* p, f32x4 d){
  asm volatile("global_store_dwordx4 %0, %1, off sc1" :: "v"(p), "v"(d) : "memory");
}
__device__ __forceinline__ void u32store_mall(u32* p, u32 v){
  __hip_atomic_store(p, v, __ATOMIC_RELAXED, __HIP_MEMORY_SCOPE_AGENT);
}
__device__ __forceinline__ u32 u32load_mall(const u32* p){
  return __hip_atomic_load(p, __ATOMIC_RELAXED, __HIP_MEMORY_SCOPE_AGENT);
}

// ---------------- (1) weight/R convert: 64x64 LDS-tiled transposes ----------------
// blocks 0..255: W tiles -> Wa (plain f16 copy) + Wb (transpose).
// blocks 256..383: R tiles -> Rt (transpose).
__global__ __launch_bounds__(256) void cvt_wr(
    const float* __restrict__ W, const float* __restrict__ R,
    _Float16* __restrict__ Wa, _Float16* __restrict__ Wb,
    _Float16* __restrict__ Rt){
  __shared__ _Float16 tl[64][65];
  const int tr = threadIdx.x >> 6;     // 0..3
  const int tc = threadIdx.x & 63;
  if (blockIdx.x < 256){
    const int k0 = (blockIdx.x >> 4) << 6, u0 = (blockIdx.x & 15) << 6;
    #pragma unroll
    for (int r8 = 0; r8 < 16; ++r8){
      const int row = r8*4 + tr;
      const float v = W[(size_t)(k0 + row)*1024 + u0 + tc];
      Wa[(size_t)(k0 + row)*1024 + u0 + tc] = (_Float16)v;   // Wa[x][y]=W[x][y]
      tl[row][tc] = (_Float16)v;
    }
    __syncthreads();
    #pragma unroll
    for (int r8 = 0; r8 < 16; ++r8){
      const int jrow = r8*4 + tr;
      Wb[(size_t)(u0 + jrow)*1024 + k0 + tc] = tl[tc][jrow]; // Wb[u][k]=W[k][u]
    }
  } else {
    const int bid = blockIdx.x - 256;
    const int f0 = (bid >> 4) << 6, u0 = (bid & 15) << 6;
    #pragma unroll
    for (int r8 = 0; r8 < 16; ++r8){
      const int row = r8*4 + tr;
      tl[row][tc] = (_Float16)R[(size_t)(f0 + row)*1024 + u0 + tc];
    }
    __syncthreads();
    #pragma unroll
    for (int r8 = 0; r8 < 16; ++r8){
      const int jrow = r8*4 + tr;
      Rt[(size_t)(u0 + jrow)*512 + f0 + tc] = tl[tc][jrow];  // Rt[u][f]=R[f][u]
    }
  }
}

// ---------------- (2) h prepass: coalesced LDS staging + MFMA ----------------
__global__ __launch_bounds__(512, 2) void h_prepass(
    const float* __restrict__ inputs, const _Float16* __restrict__ Rt,
    const float* __restrict__ bias, float* __restrict__ out){
  __shared__ char ilds[64 * 1024];     // [64 b][512 f] f16, 16B-XOR-swizzled
  const int t   = blockIdx.x;
  const int tid = threadIdx.x;

  // stage: 8 iters; lanes contiguous in f -> fully coalesced float4 loads
  #pragma unroll
  for (int it = 0; it < 8; ++it){
    const int i = tid + it*512;        // 16B-chunk index 0..4095
    const int row = i >> 6, ch = i & 63;
    const float* ip = inputs + (size_t)row*262144 + (size_t)t*512 + ch*8;
    float4 xa = *(const float4*)ip, xb = *(const float4*)(ip + 4);
    f16x8 a;
    a[0]=(_Float16)xa.x; a[1]=(_Float16)xa.y; a[2]=(_Float16)xa.z; a[3]=(_Float16)xa.w;
    a[4]=(_Float16)xb.x; a[5]=(_Float16)xb.y; a[6]=(_Float16)xb.z; a[7]=(_Float16)xb.w;
    *(f16x8*)(ilds + row*1024 + ((ch*16) ^ ((row & 7) << 4))) = a;
  }
  __syncthreads();

  const int w  = tid >> 6, l = tid & 63;
  const int lr = l & 15, lg = l >> 4;
  const int b0 = (w >> 1) * 16;        // 16 batch rows
  const int c0 = (w & 1) * 512;        // 512 unit cols

  f32x4 acc[32];
  #pragma unroll
  for (int n = 0; n < 32; ++n) acc[n] = (f32x4){0.f,0.f,0.f,0.f};

  for (int kc = 0; kc < 16; ++kc){
    const int row = b0 + lr;
    f16x8 a = *(const f16x8*)(ilds + row*1024 + ((kc*64 + lg*16) ^ ((row & 7) << 4)));
    const _Float16* rp = Rt + (size_t)(c0 + lr)*512 + kc*32 + lg*8;
    #pragma unroll
    for (int n = 0; n < 32; ++n){
      f16x8 b = *(const f16x8*)(rp + (size_t)n*(16*512));
      acc[n] = mfma16(a, b, acc[n]);
    }
  }
  #pragma unroll
  for (int n = 0; n < 32; ++n){
    const int u = c0 + n*16 + lr;
    const float bu = bias[u];
    #pragma unroll
    for (int j = 0; j < 4; ++j)
      out[(size_t)t*65536 + (size_t)(b0 + lg*4 + j)*1024 + u] = acc[n][j] + bu;
  }
}

// ---------------- (3) scan — FROZEN from v16 ----------------
__global__ __launch_bounds__(512, 2) void irl_scan(
    const _Float16* __restrict__ Wa, const _Float16* __restrict__ Wb,
    const float* __restrict__ x0, float* __restrict__ out,
    unsigned short* __restrict__ st, unsigned* __restrict__ flags)
{
  __shared__ char alds[16 * 2048];     // row-group state [16 rows][1024 k], swizzled

  const int tid = threadIdx.x;
  const int w   = tid >> 6;            // wave = n-tile owner AND producer-w stager
  const int l   = tid & 63;
  const int lr  = l & 15;
  const int lg  = l >> 4;
  const int cblk = blockIdx.x & 7;     // col-split (producer id in group)
  const int grp  = blockIdx.x >> 3;    // row-group
  const int col0 = cblk << 7;          // 128 cols per block
  const int r0   = grp << 4;           // 16 rows per group
  const int u    = col0 + w*16 + lr;
  unsigned* myf  = flags + (((grp << 3) + cblk) << 4);

  // ---- state[0] <- x0 : tagged 16B chunks into slot 0 (tag for t=0 is 1) ----
  if (tid < 256){
    const int row = tid >> 4, ch = tid & 15;
    chunk16 c;
    #pragma unroll
    for (int j = 0; j < 8; ++j) c.h[j] = (_Float16)x0[col0 + ch*8 + j];
    c.d[3] |= 0x10000u;
    gstore_sc1_b128((char*)st + (size_t)(r0 + row)*2048 + col0*2 + ch*16, c.f);
  }
  waitvm0();
  __syncthreads();
  if (tid == 0) u32store_mall(myf, 1u);
  // one-time init gate (proven r11/r13 pattern): kills cross-replay stale slot 0
  if (tid < 64){
    const int src = (tid < 8) ? tid : 0;
    const unsigned* pf = flags + (((grp << 3) + src) << 4);
    for (;;){
      unsigned v = u32load_mall(pf);
      if (__all((int)(v >= 1u))) break;
      __builtin_amdgcn_s_sleep(1);
    }
  }
  __syncthreads();

  // h prefetch for t=0
  float hv[4];
  #pragma unroll
  for (int j = 0; j < 4; ++j)
    hv[j] = out[(size_t)(r0 + lg*4 + j)*1024 + u];

  unsigned cur = 0;
  int pp = -1;
  f16x8 wf[32];                        // current phase, full K=1024
  for (int t = 0; t < TSTEPS; ++t){
    const int ph = (t >> 6) & 1;       // 1 -> W (Wb), 0 -> W^T (Wa)
    if (ph != pp){
      pp = ph;
      const _Float16* Wsel = ph ? Wb : Wa;
      #pragma unroll
      for (int i = 0; i < 32; ++i)
        wf[i] = *(const f16x8*)(Wsel + (size_t)u*1024 + i*32 + lg*8);
    }

    // ---- tag-verified stage: gate merged into the data load (retry until gen t) ----
    const u32 tag_exp = (((u32)t >> 1) & 1u) ^ 1u;
    const char* base = (const char*)st + ((size_t)cur << 17)
                     + (size_t)r0*2048 + w*256 + lr*16;
    chunk16 q[4];
    for (;;){
      #pragma unroll
      for (int i = 0; i < 4; ++i)
        q[i].f = gload_sc1_b128(base + (size_t)(i*4 + lg)*2048);
      waitvm0();
      int ok = 1;
      #pragma unroll
      for (int i = 0; i < 4; ++i)
        ok &= (int)(((q[i].d[3] >> 16) & 1u) == tag_exp);
      if (__all(ok)) break;
      __builtin_amdgcn_s_sleep(1);
    }
    __syncthreads();                   // prev-step MFMA reads of alds complete
    #pragma unroll
    for (int i = 0; i < 4; ++i){
      const int row = i*4 + lg, c = w*256 + lr*16;
      *(f32x4*)(alds + row*2048 + (c ^ ((row & 7) << 4))) = q[i].f;
    }
    __syncthreads();

    // ---- h prefetch for t+1 (plain loads; miss overlaps MFMA + next poll) ----
    float hvn[4];
    {
      const int tn = (t < TSTEPS - 1) ? t + 1 : t;
      #pragma unroll
      for (int j = 0; j < 4; ++j)
        hvn[j] = out[(size_t)tn*65536 + (size_t)(r0 + lg*4 + j)*1024 + u];
    }

    // ---- recurrent GEMM: 32 MFMAs, 2 chains ----
    f32x4 ac0 = {0.f,0.f,0.f,0.f}, ac1 = ac0;
    #pragma unroll
    for (int i = 0; i < 32; i += 2){
      f16x8 a0 = *(const f16x8*)(alds + lr*2048 + ((i*64 + lg*16) ^ ((lr & 7) << 4)));
      f16x8 a1 = *(const f16x8*)(alds + lr*2048 + (((i+1)*64 + lg*16) ^ ((lr & 7) << 4)));
      ac0 = mfma16(a0, wf[i], ac0);
      ac1 = mfma16(a1, wf[i+1], ac1);
    }
    const f32x4 acc = ac0 + ac1;

    // ---- epilogue: all tagged state stores FIRST, then plain (L2) out stores ----
    char* nbB = (char*)st + ((size_t)(cur ^ 1u) << 17);
    const u32 tag_nxt = (((u32)(t + 1) >> 1) & 1u) ^ 1u;
    float vv[4];
    chunk16 cst[4];
    #pragma unroll
    for (int j = 0; j < 4; ++j){
      const float v = tanhf(acc[j] + hv[j]);
      vv[j] = v;
      pk2 me; me.h[0] = (_Float16)v; me.h[1] = (_Float16)0.f;
      const u32 two = (me.u & 0xffffu) | ((u32)__shfl_xor((int)me.u, 1) << 16);
      const u32 lo4 = two, hi4 = (u32)__shfl_xor((int)two, 2);
      cst[j].d[0] = lo4;
      cst[j].d[1] = hi4;
      cst[j].d[2] = (u32)__shfl_xor((int)lo4, 4);
      cst[j].d[3] = ((u32)__shfl_xor((int)hi4, 4) & ~0x10000u) | (tag_nxt << 16);
    }
    if (!(lr & 7)){
      #pragma unroll
      for (int j = 0; j < 4; ++j)
        gstore_sc1_b128(nbB + (size_t)(r0 + lg*4 + j)*2048 + (size_t)(u & ~7)*2, cst[j].f);
    }
    #pragma unroll
    for (int j = 0; j < 4; ++j)       // PLAIN stores: ack at local L2, lazy HBM drain
      out[(size_t)t*65536 + (size_t)(r0 + lg*4 + j)*1024 + u] = vv[j];

    #pragma unroll
    for (int j = 0; j < 4; ++j) hv[j] = hvn[j];
    cur ^= 1u;
  }
}

extern "C" void kernel_launch(void* const* d_in, const int* in_sizes, int n_in,
                              void* d_out, int out_size, void* d_ws, size_t ws_size,
                              hipStream_t stream){
  (void)in_sizes; (void)n_in; (void)out_size; (void)ws_size;
  const float* inputs = (const float*)d_in[0];   // [64,512,512] f32
  const float* R      = (const float*)d_in[1];   // [512,1024]  f32
  const float* W      = (const float*)d_in[2];   // [1024,1024] f32
  const float* bias   = (const float*)d_in[3];   // [1024]      f32
  const float* x0     = (const float*)d_in[4];   // [1024]      f32
  float* out = (float*)d_out;                    // [512,64,1024] f32 (h, then states)

  char* ws = (char*)d_ws;
  unsigned* flags     = (unsigned*)ws;                    // 4 KB (init gate only)
  unsigned short* st  = (unsigned short*)(ws + 4096);     // 2 x 64x1024 fp16 (256 KB)
  _Float16* Rt = (_Float16*)(ws + (512<<10));             // 1 MB  @ 0.5 MB
  _Float16* Wa = (_Float16*)(ws + (2u<<20));              // 2 MB  @ 2 MB
  _Float16* Wb = (_Float16*)(ws + (4u<<20));              // 2 MB  @ 4 MB

  (void)hipMemsetAsync(flags, 0, 4096, stream);
  hipLaunchKernelGGL(cvt_wr,    dim3(384),  dim3(256), 0, stream, W, R, Wa, Wb, Rt);
  hipLaunchKernelGGL(h_prepass, dim3(512),  dim3(512), 0, stream, inputs, Rt, bias, out);
  hipLaunchKernelGGL(irl_scan,  dim3(32),   dim3(512), 0, stream, Wa, Wb, x0, out, st, flags);
}